// Round 14
// baseline (1215.425 us; speedup 1.0000x reference)
//
#include <hip/hip_runtime.h>

constexpr int Bn = 16, Cn = 256, Hn = 96, Wn = 96, Pn = Hn * Wn; // 9216

#define DI static __device__ __forceinline__

struct alignas(16) U4 { unsigned a, b, c, d; };

typedef _Float16 f16x8 __attribute__((ext_vector_type(8)));
typedef float f32x4 __attribute__((ext_vector_type(4)));

#define GLOAD16(g, l) __builtin_amdgcn_global_load_lds( \
    (const __attribute__((address_space(1))) void*)(g), \
    (__attribute__((address_space(3))) void*)(l), 16, 0, 0)

// ---------- weight transform: w fp32 [co][c][11] -> wt fp16 [t][co_off+co][256] ----------
__global__ void k_wt16(const float* __restrict__ w, _Float16* __restrict__ wt,
                       int co_n, int co_off, int co_tot) {
    int idx = blockIdx.x * 256 + threadIdx.x;
    if (idx >= co_n * 2816) return;
    int co = idx / 2816;
    int r  = idx - co * 2816;
    int c  = r / 11, t = r - c * 11;
    wt[((size_t)t * co_tot + co_off + co) * 256 + c] = (_Float16)w[idx];
}

// ---------- x split: fp32 [b][c][p] -> fp16 hi/lo channels-last [b][p][256] (+ transposed) ----------
__global__ __launch_bounds__(256) void k_xsplit(const float* __restrict__ x,
                                                _Float16* __restrict__ xh, _Float16* __restrict__ xl,
                                                _Float16* __restrict__ xhT, _Float16* __restrict__ xlT) {
    int b = blockIdx.y;
    int tid = threadIdx.x;
    int p = blockIdx.x * 128 + (tid >> 1);
    int half = tid & 1;
    int h = p / 96, w = p - h * 96;
    int pT = w * 96 + h;
    const float* xb = x + (size_t)b * Cn * Pn + p;
    size_t ob  = ((size_t)b * Pn + p) * 256;
    size_t obT = ((size_t)b * Pn + pT) * 256;
    for (int it = 0; it < 16; ++it) {
        int c0 = it * 16 + half * 8;
        f16x8 vh_, vl_;
#pragma unroll
        for (int i = 0; i < 8; ++i) {
            float f = xb[(size_t)(c0 + i) * Pn];
            _Float16 hh = (_Float16)f;
            vh_[i] = hh;
            vl_[i] = (_Float16)(f - (float)hh);
        }
        *(f16x8*)(xh + ob + c0) = vh_;
        *(f16x8*)(xl + ob + c0) = vl_;
        *(f16x8*)(xhT + obT + c0) = vh_;
        *(f16x8*)(xlT + obT + c0) = vl_;
    }
}

// ---------- V conv (both families): wave tile 96px x 64co (disjoint px quarters) ----------
// X fp16 ch-last [b][9216][256]; WT fp16 [11][256][256]; out fp16 [b][256][9216]
__global__ __launch_bounds__(256, 2) void k_conv_v(const _Float16* __restrict__ X0,
                                                   const _Float16* __restrict__ W0,
                                                   const float* __restrict__ b0a,
                                                   _Float16* __restrict__ o0,
                                                   const _Float16* __restrict__ X1,
                                                   const _Float16* __restrict__ W1,
                                                   const float* __restrict__ b1a,
                                                   _Float16* __restrict__ o1) {
    __shared__ char sm_raw[57344]; // 2 bufs x [4 stripes][112 rows][64B]; epilogue aliases 49152B
    const int tid = threadIdx.x;
    const int lane = tid & 63, wave = tid >> 6;   // wave = px quarter (96 px), owns all 64 co
    const int l15 = lane & 15, kg = lane >> 4;
    // bijective XCD-chunked swizzle over grid (24,4,32); co0 innermost for L2 X-reuse
    int fid = blockIdx.x + 24 * (blockIdx.y + 4 * blockIdx.z);
    int swz = (fid & 7) * 384 + (fid >> 3);
    const int co0 = (swz & 3) * 64;
    int rest = swz >> 2;
    const int bx = rest % 24;
    const int z = rest / 24;
    const int fam = z >> 4, b = z & 15;
    const _Float16* X  = fam ? X1 : X0;
    const _Float16* WT = fam ? W1 : W0;
    const float* bias  = fam ? b1a : b0a;
    _Float16* out      = fam ? o1 : o0;

    // zero halo pad rows: 2 bufs x 4 stripes x 2 ends x 128 dwords
    for (int zz = tid; zz < 2048; zz += 256) {
        int bufo = (zz >> 10) * 28672;
        int s = (zz >> 7) & 7, off = zz & 127;
        int Rbase = (s >> 1) * 112 + ((s & 1) ? 104 : 0);
        *(unsigned*)(sm_raw + bufo + Rbase * 64 + off * 4) = 0u;
    }

    f32x4 acc[4][6];
#pragma unroll
    for (int mf = 0; mf < 4; ++mf) {
        const float* bp = bias + co0 + mf * 16 + kg * 4;
        f32x4 bv = { bp[0], bp[1], bp[2], bp[3] };
#pragma unroll
        for (int nf = 0; nf < 6; ++nf) acc[mf][nf] = bv;
    }

    const _Float16* Xb = X + ((size_t)b * Pn + bx * 384) * 256;
    const _Float16* Wb = WT + (size_t)(co0 + l15) * 256 + kg * 8;

    auto STAGE = [&](int c0, int bufo) {
        for (int i = wave; i < 24; i += 4) {
            int s = i / 6, wch = i - s * 6;
            int row_local = 8 + wch * 16 + (lane >> 2);
            int kchunk = (lane & 3) ^ ((row_local >> 1) & 3);
            const _Float16* src = Xb + ((size_t)(s * 96 + row_local - 8)) * 256 + c0 + kchunk * 8;
            char* dst = sm_raw + bufo + (s * 112 + 8 + wch * 16) * 64;
            GLOAD16(src, dst);
        }
    };
    auto LDA = [&](f16x8* slot, const _Float16* tp) {
#pragma unroll
        for (int mf = 0; mf < 4; ++mf) slot[mf] = *(const f16x8*)(tp + mf * 4096);
    };
    // one address per tap; wave's px quarter = stripe `wave`; frag idx folds into offsets
    auto LDB = [&](f16x8* dst, const char* Bb, int T) {
        int rl0 = 3 + l15 + T; // swizzle term invariant in nf
        const char* bp = Bb + (wave * 112 + rl0) * 64 + ((kg ^ ((rl0 >> 1) & 3)) << 4);
#pragma unroll
        for (int nf = 0; nf < 6; ++nf)
            dst[nf] = *(const f16x8*)(bp + nf * 1024);
    };

    STAGE(0, 0);
    __syncthreads();

    int cur = 0;
    for (int s8 = 0; s8 < 8; ++s8) {
        const int c0 = s8 * 32;
        const _Float16* wc = Wb + c0;
        f16x8 afc[4], afn[4];
        LDA(afc, wc);
        if (s8 < 7) STAGE(c0 + 32, (cur ^ 1) * 28672);
        const char* Bb = sm_raw + cur * 28672;
        f16x8 bf[6];
#pragma unroll
        for (int t = 0; t < 11; ++t) {
            if (t < 10) LDA(afn, wc + (t + 1) * 65536);
            LDB(bf, Bb, t);
            __builtin_amdgcn_s_setprio(1);
#pragma unroll
            for (int mf = 0; mf < 4; ++mf)
#pragma unroll
                for (int nf = 0; nf < 6; ++nf)
                    acc[mf][nf] = __builtin_amdgcn_mfma_f32_16x16x32_f16(afc[mf], bf[nf], acc[mf][nf], 0, 0, 0);
            __builtin_amdgcn_s_setprio(0);
            if (t < 10) {
#pragma unroll
                for (int mf = 0; mf < 4; ++mf) afc[mf] = afn[mf];
            }
        }
        __syncthreads();
        cur ^= 1;
    }

    // epilogue: retile to channels-first fp16 via LDS [64][384]
    _Float16* sb = (_Float16*)sm_raw;
#pragma unroll
    for (int mf = 0; mf < 4; ++mf)
#pragma unroll
        for (int nf = 0; nf < 6; ++nf)
#pragma unroll
            for (int r = 0; r < 4; ++r) {
                int row = mf * 16 + kg * 4 + r;
                int p = wave * 96 + nf * 16 + l15;
                sb[row * 384 + p] = (_Float16)acc[mf][nf][r];
            }
    __syncthreads();
    for (int k = 0; k < 12; ++k) {
        int ci = tid + k * 256;           // 0..3071 chunks of 16B
        int row = ci / 48, ch = ci - row * 48;
        U4 v = *(const U4*)(sm_raw + row * 768 + ch * 16);
        *(U4*)(out + ((size_t)b * 256 + co0 + row) * Pn + bx * 384 + ch * 8) = v;
    }
}

// ---------- fused Q+K conv (both families): wave tile 48px x 64co, 2-pass fp16 ----------
__global__ __launch_bounds__(256, 2) void k_conv_qk(const _Float16* __restrict__ Xh0,
                                                    const _Float16* __restrict__ Xl0,
                                                    const _Float16* __restrict__ W0,
                                                    const float* __restrict__ bq0, const float* __restrict__ bk0,
                                                    _Float16* __restrict__ q0, _Float16* __restrict__ k0,
                                                    const _Float16* __restrict__ Xh1,
                                                    const _Float16* __restrict__ Xl1,
                                                    const _Float16* __restrict__ W1,
                                                    const float* __restrict__ bq1, const float* __restrict__ bk1,
                                                    _Float16* __restrict__ q1, _Float16* __restrict__ k1) {
    __shared__ char sm_raw[57344]; // 2 bufs x [4 stripes][112][64B] (hi: 0-1, lo: 2-3); epilogue aliases 24576B
    const int tid = threadIdx.x;
    const int lane = tid & 63, wave = tid >> 6;   // wave = px quarter (48 px), owns all 64 co
    const int l15 = lane & 15, kg = lane >> 4;
    // bijective XCD-chunked swizzle over grid (48,1,32): 1536 % 8 == 0
    int fid = blockIdx.x + 48 * blockIdx.z;
    int swz = (fid & 7) * 192 + (fid >> 3);
    const int bx = swz % 48;
    const int zz0 = swz / 48;
    const int fam = zz0 >> 4, b = zz0 & 15;
    const _Float16* Xh = fam ? Xh1 : Xh0;
    const _Float16* Xl = fam ? Xl1 : Xl0;
    const _Float16* WT = fam ? W1 : W0;
    const float* bq = fam ? bq1 : bq0;
    const float* bk = fam ? bk1 : bk0;
    _Float16* q16 = fam ? q1 : q0;
    _Float16* k16 = fam ? k1 : k0;

    for (int z = tid; z < 2048; z += 256) {
        int bufo = (z >> 10) * 28672;
        int s = (z >> 7) & 7, off = z & 127;
        int Rbase = (s >> 1) * 112 + ((s & 1) ? 104 : 0);
        *(unsigned*)(sm_raw + bufo + Rbase * 64 + off * 4) = 0u;
    }

    f32x4 acc[4][3];
#pragma unroll
    for (int mf = 0; mf < 4; ++mf) {
        int cb = mf * 16 + kg * 4;
        f32x4 bv;
#pragma unroll
        for (int r = 0; r < 4; ++r) {
            int co_l = cb + r;
            bv[r] = (co_l < 32) ? bq[co_l] : bk[co_l - 32];
        }
#pragma unroll
        for (int nf = 0; nf < 3; ++nf) acc[mf][nf] = bv;
    }

    const _Float16* Xbh = Xh + ((size_t)b * Pn + bx * 192) * 256;
    const _Float16* Xbl = Xl + ((size_t)b * Pn + bx * 192) * 256;
    const _Float16* Wb = WT + (size_t)l15 * 256 + kg * 8;

    auto STAGE = [&](int c0, int bufo) {
        for (int i = wave; i < 24; i += 4) {
            int a = i / 12, rr = (i / 6) & 1, wch = i % 6;
            int row_local = 8 + wch * 16 + (lane >> 2);
            int kchunk = (lane & 3) ^ ((row_local >> 1) & 3);
            const _Float16* base = (a == 0) ? Xbh : Xbl;
            const _Float16* src = base + ((size_t)(rr * 96 + row_local - 8)) * 256 + c0 + kchunk * 8;
            char* dst = sm_raw + bufo + ((a * 2 + rr) * 112 + 8 + wch * 16) * 64;
            GLOAD16(src, dst);
        }
    };
    auto LDA = [&](f16x8* slot, const _Float16* tp) {
#pragma unroll
        for (int mf = 0; mf < 4; ++mf) slot[mf] = *(const f16x8*)(tp + mf * 4096);
    };
    // wave's 48px: row-stripe wave>>1, px offset (wave&1)*48; hi at stripe, lo at +14336
    auto LDBHL = [&](f16x8* dh, f16x8* dl, const char* Bb, int T) {
        int rl0 = 3 + (wave & 1) * 48 + l15 + T;
        const char* bp = Bb + ((wave >> 1) * 112 + rl0) * 64 + ((kg ^ ((rl0 >> 1) & 3)) << 4);
#pragma unroll
        for (int nf = 0; nf < 3; ++nf) {
            dh[nf] = *(const f16x8*)(bp + nf * 1024);
            dl[nf] = *(const f16x8*)(bp + 14336 + nf * 1024);
        }
    };

    STAGE(0, 0);
    __syncthreads();

    int cur = 0;
    for (int s8 = 0; s8 < 8; ++s8) {
        const int c0 = s8 * 32;
        const _Float16* wc = Wb + c0;
        f16x8 afc[4], afn[4];
        LDA(afc, wc);
        if (s8 < 7) STAGE(c0 + 32, (cur ^ 1) * 28672);
        const char* Bb = sm_raw + cur * 28672;
#pragma unroll
        for (int t = 0; t < 11; ++t) {
            if (t < 10) LDA(afn, wc + (t + 1) * 16384);
            f16x8 bh[3], bl[3];
            LDBHL(bh, bl, Bb, t);
            __builtin_amdgcn_s_setprio(1);
#pragma unroll
            for (int mf = 0; mf < 4; ++mf)
#pragma unroll
                for (int nf = 0; nf < 3; ++nf) {
                    acc[mf][nf] = __builtin_amdgcn_mfma_f32_16x16x32_f16(afc[mf], bh[nf], acc[mf][nf], 0, 0, 0);
                    acc[mf][nf] = __builtin_amdgcn_mfma_f32_16x16x32_f16(afc[mf], bl[nf], acc[mf][nf], 0, 0, 0);
                }
            __builtin_amdgcn_s_setprio(0);
            if (t < 10) {
#pragma unroll
                for (int mf = 0; mf < 4; ++mf) afc[mf] = afn[mf];
            }
        }
        __syncthreads();
        cur ^= 1;
    }

    // epilogue: retile to [192 p][32 c] fp16 in LDS, then coalesced 16B stores
    __syncthreads();
    _Float16* sq = (_Float16*)sm_raw;            // [192][32]
    _Float16* sk = (_Float16*)(sm_raw + 12288);  // [192][32]
#pragma unroll
    for (int mf = 0; mf < 4; ++mf) {
        int cb = mf * 16 + kg * 4;
#pragma unroll
        for (int r = 0; r < 4; ++r) {
            int co_l = cb + r;
            _Float16* arr = (co_l < 32) ? sq : sk;
            int c = co_l & 31;
#pragma unroll
            for (int nf = 0; nf < 3; ++nf) {
                int p = wave * 48 + nf * 16 + l15;
                arr[p * 32 + c] = (_Float16)acc[mf][nf][r];
            }
        }
    }
    __syncthreads();
    for (int j = 0; j < 6; ++j) {
        int idx = tid + j * 256;      // 0..1535 16B chunks
        int mtx = idx >= 768;
        int e = idx - mtx * 768;
        int p = e >> 2, cg2 = e & 3;
        U4 v = *(const U4*)(sm_raw + mtx * 12288 + p * 64 + cg2 * 16);
        _Float16* dstb = mtx ? k16 : q16;
        *(U4*)(dstb + ((size_t)b * Pn + bx * 192 + p) * 32 + cg2 * 8) = v;
    }
}

// ---------- attention helpers ----------
DI void stage_qk16(const _Float16* qg, const _Float16* kg, char* Lq, char* Lk, int tid) {
    for (int i = tid; i < 768; i += 256) {
        int mtx = i >= 384;
        int e = i - mtx * 384;
        int p = e >> 2, ch = e & 3;
        const _Float16* src = (mtx ? kg : qg) + p * 32 + ch * 8;
        f16x8 v = *(const f16x8*)src;
        char* dst = (mtx ? Lk : Lq) + p * 64 + ((ch ^ ((p >> 1) & 3)) << 4);
        *(f16x8*)dst = v;
    }
}

DI void mfma_e(const char* Lq, const char* Lk, float* Ef, int lane, int wave) {
    int l15 = lane & 15, kg = lane >> 4;
    int wm = wave >> 1, wn = wave & 1;
    f16x8 qa[3], kb[3];
#pragma unroll
    for (int i = 0; i < 3; ++i) {
        int pr = wm * 48 + i * 16 + l15;
        qa[i] = *(const f16x8*)(Lq + pr * 64 + ((kg ^ ((pr >> 1) & 3)) << 4));
        int pc = wn * 48 + i * 16 + l15;
        kb[i] = *(const f16x8*)(Lk + pc * 64 + ((kg ^ ((pc >> 1) & 3)) << 4));
    }
#pragma unroll
    for (int i = 0; i < 3; ++i)
#pragma unroll
        for (int j = 0; j < 3; ++j) {
            f32x4 a = { 0.f, 0.f, 0.f, 0.f };
            a = __builtin_amdgcn_mfma_f32_16x16x32_f16(qa[i], kb[j], a, 0, 0, 0);
#pragma unroll
            for (int r = 0; r < 4; ++r) {
                int row = wm * 48 + i * 16 + kg * 4 + r;
                int col = wn * 48 + j * 16 + l15;
                Ef[row * 97 + col] = a[r];
            }
        }
}

// ---------- P1: h-attention stats (per b,w), wave-parallel 2-way row split ----------
__global__ __launch_bounds__(256) void k_p1(const _Float16* __restrict__ q16, const _Float16* __restrict__ k16,
                                            float* __restrict__ mh, float* __restrict__ lh) {
    __shared__ char L[49536];
    float* Ef = (float*)L;
    char* Lq = L + 37248;
    char* Lk = L + 43392;
    const int tid = threadIdx.x, lane = tid & 63, wave = tid >> 6;
    const int w = blockIdx.x, b = blockIdx.y;
    const _Float16* qg = q16 + ((size_t)b * Pn + w * 96) * 32;
    const _Float16* kg = k16 + ((size_t)b * Pn + w * 96) * 32;
    stage_qk16(qg, kg, Lq, Lk, tid);
    __syncthreads();
    mfma_e(Lq, Lk, Ef, lane, wave);
    __syncthreads();
    if (tid < 96) Ef[tid * 97 + tid] = -INFINITY; // diag mask
    __syncthreads();
    float* red  = (float*)Lq;  // dead after mfma_e
    float* red2 = red + 192;
    if (tid < 192) {
        int r = tid >> 1, hf = tid & 1;
        const float* er = Ef + r * 97 + hf * 48;
        float m = -INFINITY;
        for (int j = 0; j < 48; ++j) m = fmaxf(m, er[j]);
        red[tid] = m;
    }
    __syncthreads();
    if (tid < 192) {
        int r = tid >> 1, hf = tid & 1;
        float m = fmaxf(red[r * 2], red[r * 2 + 1]);
        const float* er = Ef + r * 97 + hf * 48;
        float s = 0.f;
        for (int j = 0; j < 48; ++j) s += __expf(er[j] - m);
        red2[tid] = s;
    }
    __syncthreads();
    if (tid < 96) {
        mh[((size_t)b * 96 + w) * 96 + tid] = fmaxf(red[tid * 2], red[tid * 2 + 1]);
        lh[((size_t)b * 96 + w) * 96 + tid] = red2[tid * 2] + red2[tid * 2 + 1];
    }
}

// ---------- P2: w-attention stats+merge+PV (per b,h); writes out_w fp16 to scratch ----------
__global__ __launch_bounds__(256) void k_p2(const _Float16* __restrict__ q16, const _Float16* __restrict__ k16,
                                            const _Float16* __restrict__ V,
                                            const float* __restrict__ mh, const float* __restrict__ lh,
                                            float* __restrict__ mo, float* __restrict__ lo,
                                            _Float16* __restrict__ outw) {
    __shared__ char L[56448];
    float* Ef = (float*)L;          // [96][97] f32
    char* LA  = L + 37248;          // A fp16 [96][12 chunks]
    char* Lq  = L + 37248;          // overlaps LA (dead before A written)
    char* Lk  = L + 43392;
    float* Marr = (float*)(L + 55680);
    float* Linv = (float*)(L + 56064);
    const int tid = threadIdx.x, lane = tid & 63, wave = tid >> 6;
    const int l15 = lane & 15, kg = lane >> 4;
    const int h = blockIdx.x, b = blockIdx.y;
    const _Float16* qg = q16 + ((size_t)b * Pn + h * 96) * 32;
    const _Float16* kgp = k16 + ((size_t)b * Pn + h * 96) * 32;
    stage_qk16(qg, kgp, Lq, Lk, tid);
    __syncthreads();
    mfma_e(Lq, Lk, Ef, lane, wave);
    __syncthreads();
    float* red  = (float*)Lk;  // dead after mfma_e; A-build happens later
    float* red2 = red + 192;
    if (tid < 192) {
        int r = tid >> 1, hf = tid & 1;
        const float* er = Ef + r * 97 + hf * 48;
        float m = -INFINITY;
        for (int j = 0; j < 48; ++j) m = fmaxf(m, er[j]);
        red[tid] = m;
    }
    __syncthreads();
    if (tid < 192) {
        int r = tid >> 1, hf = tid & 1;
        float m = fmaxf(red[r * 2], red[r * 2 + 1]);
        const float* er = Ef + r * 97 + hf * 48;
        float s = 0.f;
        for (int j = 0; j < 48; ++j) s += __expf(er[j] - m);
        red2[tid] = s;
    }
    __syncthreads();
    if (tid < 96) {
        int wq = tid;
        float mw = fmaxf(red[wq * 2], red[wq * 2 + 1]);
        float lw = red2[wq * 2] + red2[wq * 2 + 1];
        float mhv = mh[((size_t)b * 96 + wq) * 96 + h];
        float lhv = lh[((size_t)b * 96 + wq) * 96 + h];
        float m = fmaxf(mhv, mw);
        float l = lhv * __expf(mhv - m) + lw * __expf(mw - m);
        mo[((size_t)b * 96 + h) * 96 + wq] = m;
        lo[((size_t)b * 96 + h) * 96 + wq] = l;
        Marr[wq] = m;
        Linv[wq] = 1.f / l;
    }
    __syncthreads();
    if (tid < 192) {
        int r = tid >> 1, half = tid & 1;
        float m = Marr[r], li = Linv[r];
        const float* er = Ef + r * 97;
        for (int cc = 0; cc < 6; ++cc) {
            int chunk = half * 6 + cc;
            f16x8 av;
#pragma unroll
            for (int jj = 0; jj < 8; ++jj)
                av[jj] = (_Float16)(__expf(er[chunk * 8 + jj] - m) * li);
            *(f16x8*)(LA + r * 192 + ((chunk ^ ((r >> 1) & 3)) << 4)) = av;
        }
    }
    __syncthreads();
    // PV: out_w[c][wq] = sum_W V[c][W] * A[wq][W]
    f32x4 acc[4][6];
#pragma unroll
    for (int mf = 0; mf < 4; ++mf)
#pragma unroll
        for (int nf = 0; nf < 6; ++nf) acc[mf][nf] = f32x4{ 0.f, 0.f, 0.f, 0.f };
    const _Float16* vb = V + ((size_t)b * 256 + wave * 64 + l15) * Pn + h * 96 + kg * 8;
    f16x8 va[4][3];
#pragma unroll
    for (int mf = 0; mf < 4; ++mf)
#pragma unroll
        for (int ks = 0; ks < 3; ++ks)
            va[mf][ks] = *(const f16x8*)(vb + (size_t)mf * 16 * Pn + ks * 32);
#pragma unroll
    for (int ks = 0; ks < 3; ++ks)
#pragma unroll
        for (int nf = 0; nf < 6; ++nf) {
            int wq = nf * 16 + l15;
            int chunk = ks * 4 + kg;
            f16x8 bv = *(const f16x8*)(LA + wq * 192 + ((chunk ^ ((wq >> 1) & 3)) << 4));
#pragma unroll
            for (int mf = 0; mf < 4; ++mf)
                acc[mf][nf] = __builtin_amdgcn_mfma_f32_16x16x32_f16(va[mf][ks], bv, acc[mf][nf], 0, 0, 0);
        }
    _Float16* ob = outw + ((size_t)b * 256) * Pn + h * 96;
#pragma unroll
    for (int mf = 0; mf < 4; ++mf)
#pragma unroll
        for (int nf = 0; nf < 6; ++nf)
#pragma unroll
            for (int r = 0; r < 4; ++r) {
                int c = wave * 64 + mf * 16 + kg * 4 + r;
                ob[(size_t)c * Pn + nf * 16 + l15] = (_Float16)acc[mf][nf][r];
            }
}

// ---------- P3: h-attention PV (per b,w); writes pT fp16 [b][c][w*96+h] ----------
__global__ __launch_bounds__(256) void k_p3(const _Float16* __restrict__ q16, const _Float16* __restrict__ k16,
                                            const _Float16* __restrict__ V,
                                            const float* __restrict__ mo, const float* __restrict__ lo,
                                            _Float16* __restrict__ pT) {
    __shared__ char L[56448];
    float* Ef = (float*)L;
    char* LA  = L + 37248;
    char* Lq  = L + 37248;
    char* Lk  = L + 43392;
    float* Marr = (float*)(L + 55680);
    float* Linv = (float*)(L + 56064);
    const int tid = threadIdx.x, lane = tid & 63, wave = tid >> 6;
    const int l15 = lane & 15, kg = lane >> 4;
    const int w = blockIdx.x, b = blockIdx.y;
    const _Float16* qg = q16 + ((size_t)b * Pn + w * 96) * 32;
    const _Float16* kgp = k16 + ((size_t)b * Pn + w * 96) * 32;
    stage_qk16(qg, kgp, Lq, Lk, tid);
    __syncthreads();
    mfma_e(Lq, Lk, Ef, lane, wave);
    __syncthreads();
    if (tid < 96) {
        int hq = tid;
        Marr[hq] = mo[((size_t)b * 96 + hq) * 96 + w];
        Linv[hq] = 1.f / lo[((size_t)b * 96 + hq) * 96 + w];
    }
    __syncthreads();
    if (tid < 192) {
        int r = tid >> 1, half = tid & 1;
        float m = Marr[r], li = Linv[r];
        const float* er = Ef + r * 97;
        for (int cc = 0; cc < 6; ++cc) {
            int chunk = half * 6 + cc;
            f16x8 av;
#pragma unroll
            for (int jj = 0; jj < 8; ++jj) {
                int col = chunk * 8 + jj;
                av[jj] = (col == r) ? (_Float16)0.f
                                    : (_Float16)(__expf(er[col] - m) * li);
            }
            *(f16x8*)(LA + r * 192 + ((chunk ^ ((r >> 1) & 3)) << 4)) = av;
        }
    }
    __syncthreads();
    f32x4 acc[4][6];
#pragma unroll
    for (int mf = 0; mf < 4; ++mf)
#pragma unroll
        for (int nf = 0; nf < 6; ++nf) acc[mf][nf] = f32x4{ 0.f, 0.f, 0.f, 0.f };
    const _Float16* vb = V + ((size_t)b * 256 + wave * 64 + l15) * Pn + w * 96 + kg * 8;
    f16x8 va[4][3];
#pragma unroll
    for (int mf = 0; mf < 4; ++mf)
#pragma unroll
        for (int ks = 0; ks < 3; ++ks)
            va[mf][ks] = *(const f16x8*)(vb + (size_t)mf * 16 * Pn + ks * 32);
#pragma unroll
    for (int ks = 0; ks < 3; ++ks)
#pragma unroll
        for (int nf = 0; nf < 6; ++nf) {
            int hq = nf * 16 + l15;
            int chunk = ks * 4 + kg;
            f16x8 bv = *(const f16x8*)(LA + hq * 192 + ((chunk ^ ((hq >> 1) & 3)) << 4));
#pragma unroll
            for (int mf = 0; mf < 4; ++mf)
                acc[mf][nf] = __builtin_amdgcn_mfma_f32_16x16x32_f16(va[mf][ks], bv, acc[mf][nf], 0, 0, 0);
        }
    _Float16* pb = pT + ((size_t)b * 256) * Pn + w * 96;
#pragma unroll
    for (int mf = 0; mf < 4; ++mf)
#pragma unroll
        for (int nf = 0; nf < 6; ++nf)
#pragma unroll
            for (int r = 0; r < 4; ++r) {
                int c = wave * 64 + mf * 16 + kg * 4 + r;
                pb[(size_t)c * Pn + nf * 16 + l15] = (_Float16)acc[mf][nf][r];
            }
}

// ---------- combine: out = gamma * (pT^T + out_w) + x ----------
__global__ __launch_bounds__(256) void k_combine(const _Float16* __restrict__ pT,
                                                 const _Float16* __restrict__ ow,
                                                 const float* __restrict__ x,
                                                 const float* __restrict__ gamma,
                                                 float* __restrict__ out) {
    __shared__ float T[32][33];
    int bh = blockIdx.x, bw = blockIdx.y;
    size_t ib = (size_t)blockIdx.z * Pn;
    int tx = threadIdx.x, ty = threadIdx.y;
#pragma unroll
    for (int i = 0; i < 4; ++i) {
        int r = bw * 32 + ty + i * 8;
        T[ty + i * 8][tx] = (float)pT[ib + (size_t)r * 96 + bh * 32 + tx];
    }
    __syncthreads();
    float g = gamma[0];
#pragma unroll
    for (int i = 0; i < 4; ++i) {
        int hh = bh * 32 + ty + i * 8, ww = bw * 32 + tx;
        size_t o = ib + (size_t)hh * 96 + ww;
        out[o] = g * (T[tx][ty + i * 8] + (float)ow[o]) + x[o];
    }
}

extern "C" void kernel_launch(void* const* d_in, const int* in_sizes, int n_in,
                              void* d_out, int out_size, void* d_ws, size_t ws_size,
                              hipStream_t stream) {
    (void)in_sizes; (void)n_in; (void)out_size; (void)ws_size;
    const float* x   = (const float*)d_in[0];
    const float* wqh = (const float*)d_in[1];
    const float* bqh = (const float*)d_in[2];
    const float* wqw = (const float*)d_in[3];
    const float* bqw = (const float*)d_in[4];
    const float* wkh = (const float*)d_in[5];
    const float* bkh = (const float*)d_in[6];
    const float* wkw = (const float*)d_in[7];
    const float* bkw = (const float*)d_in[8];
    const float* wvh = (const float*)d_in[9];
    const float* bvh = (const float*)d_in[10];
    const float* wvw = (const float*)d_in[11];
    const float* bvw = (const float*)d_in[12];
    const float* gam = (const float*)d_in[13];
    float* out = (float*)d_out;

    char* ws = (char*)d_ws;
    size_t off = 0;
    auto alloc = [&](size_t bytes) -> char* {
        char* p = ws + off;
        off = (off + bytes + 255) & ~(size_t)255;
        return p;
    };
    const size_t IMG = (size_t)Bn * Cn * Pn;
    const size_t QK16 = (size_t)Bn * Pn * 32; // fp16 elements

    _Float16* xh  = (_Float16*)alloc(IMG * 2);
    _Float16* xl  = (_Float16*)alloc(IMG * 2);
    _Float16* xhT = (_Float16*)alloc(IMG * 2);
    _Float16* xlT = (_Float16*)alloc(IMG * 2);
    _Float16* qh16 = (_Float16*)alloc(QK16 * 2);
    _Float16* kh16 = (_Float16*)alloc(QK16 * 2);
    _Float16* qw16 = (_Float16*)alloc(QK16 * 2);
    _Float16* kw16 = (_Float16*)alloc(QK16 * 2);
    float* mh = (float*)alloc((size_t)Bn * Pn * 4);
    float* lh = (float*)alloc((size_t)Bn * Pn * 4);
    float* mo = (float*)alloc((size_t)Bn * Pn * 4);
    float* lo = (float*)alloc((size_t)Bn * Pn * 4);
    _Float16* wqkh  = (_Float16*)alloc((size_t)11 * 64 * 256 * 2);
    _Float16* wqkw  = (_Float16*)alloc((size_t)11 * 64 * 256 * 2);
    _Float16* wvh16 = (_Float16*)alloc((size_t)11 * 256 * 256 * 2);
    _Float16* wvw16 = (_Float16*)alloc((size_t)11 * 256 * 256 * 2);
    // aliases (stream-ordered safe): V outputs overwrite lo-split inputs after qk convs;
    // pT overwrites xhT after all h-family convs; out_w fp16 overwrites xh after all convs.
    _Float16* vh = xlT;
    _Float16* vw = xl;
    _Float16* pT = xhT;
    _Float16* ow16 = xh;

    const int gq = (32 * 2816 + 255) / 256;
    const int gv = (256 * 2816 + 255) / 256;
    k_wt16<<<gq, 256, 0, stream>>>(wqh, wqkh, 32, 0, 64);
    k_wt16<<<gq, 256, 0, stream>>>(wkh, wqkh, 32, 32, 64);
    k_wt16<<<gq, 256, 0, stream>>>(wqw, wqkw, 32, 0, 64);
    k_wt16<<<gq, 256, 0, stream>>>(wkw, wqkw, 32, 32, 64);
    k_wt16<<<gv, 256, 0, stream>>>(wvh, wvh16, 256, 0, 256);
    k_wt16<<<gv, 256, 0, stream>>>(wvw, wvw16, 256, 0, 256);

    k_xsplit<<<dim3(72, 16), 256, 0, stream>>>(x, xh, xl, xhT, xlT);

    k_conv_qk<<<dim3(48, 1, 32), 256, 0, stream>>>(xhT, xlT, wqkh, bqh, bkh, qh16, kh16,
                                                   xh,  xl,  wqkw, bqw, bkw, qw16, kw16);
    k_conv_v <<<dim3(24, 4, 32), 256, 0, stream>>>(xhT, wvh16, bvh, vh,
                                                   xh,  wvw16, bvw, vw);

    k_p1<<<dim3(96, 16), 256, 0, stream>>>(qh16, kh16, mh, lh);
    k_p2<<<dim3(96, 16), 256, 0, stream>>>(qw16, kw16, vw, mh, lh, mo, lo, ow16);
    k_p3<<<dim3(96, 16), 256, 0, stream>>>(qh16, kh16, vh, mo, lo, pT);

    k_combine<<<dim3(3, 3, Bn * Cn), dim3(32, 8), 0, stream>>>(pT, ow16, x, gam, out);
}

// Round 15
// 967.567 us; speedup vs baseline: 1.2562x; 1.2562x over previous
//
#include <hip/hip_runtime.h>

constexpr int Bn = 16, Cn = 256, Hn = 96, Wn = 96, Pn = Hn * Wn; // 9216

#define DI static __device__ __forceinline__

struct alignas(16) U4 { unsigned a, b, c, d; };

typedef _Float16 f16x8 __attribute__((ext_vector_type(8)));
typedef float f32x4 __attribute__((ext_vector_type(4)));

#define GLOAD16(g, l) __builtin_amdgcn_global_load_lds( \
    (const __attribute__((address_space(1))) void*)(g), \
    (__attribute__((address_space(3))) void*)(l), 16, 0, 0)

// ---------- weight transform: w fp32 [co][c][11] -> wt fp16 [t][co_off+co][256] ----------
__global__ void k_wt16(const float* __restrict__ w, _Float16* __restrict__ wt,
                       int co_n, int co_off, int co_tot) {
    int idx = blockIdx.x * 256 + threadIdx.x;
    if (idx >= co_n * 2816) return;
    int co = idx / 2816;
    int r  = idx - co * 2816;
    int c  = r / 11, t = r - c * 11;
    wt[((size_t)t * co_tot + co_off + co) * 256 + c] = (_Float16)w[idx];
}

// ---------- x split: fp32 [b][c][p] -> fp16 hi/lo channels-last [b][p][256] (+ transposed) ----------
__global__ __launch_bounds__(256) void k_xsplit(const float* __restrict__ x,
                                                _Float16* __restrict__ xh, _Float16* __restrict__ xl,
                                                _Float16* __restrict__ xhT, _Float16* __restrict__ xlT) {
    int b = blockIdx.y;
    int tid = threadIdx.x;
    int p = blockIdx.x * 128 + (tid >> 1);
    int half = tid & 1;
    int h = p / 96, w = p - h * 96;
    int pT = w * 96 + h;
    const float* xb = x + (size_t)b * Cn * Pn + p;
    size_t ob  = ((size_t)b * Pn + p) * 256;
    size_t obT = ((size_t)b * Pn + pT) * 256;
    for (int it = 0; it < 16; ++it) {
        int c0 = it * 16 + half * 8;
        f16x8 vh_, vl_;
#pragma unroll
        for (int i = 0; i < 8; ++i) {
            float f = xb[(size_t)(c0 + i) * Pn];
            _Float16 hh = (_Float16)f;
            vh_[i] = hh;
            vl_[i] = (_Float16)(f - (float)hh);
        }
        *(f16x8*)(xh + ob + c0) = vh_;
        *(f16x8*)(xl + ob + c0) = vl_;
        *(f16x8*)(xhT + obT + c0) = vh_;
        *(f16x8*)(xlT + obT + c0) = vl_;
    }
}

// ---------- V conv (both families): wave tile 32co x 192px, BM=64 x 384px per block ----------
// X fp16 ch-last [b][9216][256]; WT fp16 [11][256][256]; out fp16 [b][256][9216]
__global__ __launch_bounds__(256, 2) void k_conv_v(const _Float16* __restrict__ X0,
                                                   const _Float16* __restrict__ W0,
                                                   const float* __restrict__ b0a,
                                                   _Float16* __restrict__ o0,
                                                   const _Float16* __restrict__ X1,
                                                   const _Float16* __restrict__ W1,
                                                   const float* __restrict__ b1a,
                                                   _Float16* __restrict__ o1) {
    __shared__ char sm_raw[57344]; // 2 bufs x [4 stripes][112 rows][64B]; epilogue aliases 49152B
    const int tid = threadIdx.x;
    const int lane = tid & 63, wave = tid >> 6;
    const int wm = wave >> 1, wn = wave & 1;   // wm: co half, wn: px half (192 px each)
    const int l15 = lane & 15, kg = lane >> 4;
    // bijective XCD-chunked swizzle over grid (24,4,32); co0 innermost for L2 X-reuse
    int fid = blockIdx.x + 24 * (blockIdx.y + 4 * blockIdx.z);
    int swz = (fid & 7) * 384 + (fid >> 3);
    const int co0 = (swz & 3) * 64;
    int rest = swz >> 2;
    const int bx = rest % 24;
    const int z = rest / 24;
    const int fam = z >> 4, b = z & 15;
    const _Float16* X  = fam ? X1 : X0;
    const _Float16* WT = fam ? W1 : W0;
    const float* bias  = fam ? b1a : b0a;
    _Float16* out      = fam ? o1 : o0;

    // zero halo pad rows: 2 bufs x 4 stripes x 2 ends x 128 dwords
    for (int zz = tid; zz < 2048; zz += 256) {
        int bufo = (zz >> 10) * 28672;
        int s = (zz >> 7) & 7, off = zz & 127;
        int Rbase = (s >> 1) * 112 + ((s & 1) ? 104 : 0);
        *(unsigned*)(sm_raw + bufo + Rbase * 64 + off * 4) = 0u;
    }

    f32x4 acc[2][12];
#pragma unroll
    for (int mf = 0; mf < 2; ++mf) {
        const float* bp = bias + co0 + wm * 32 + mf * 16 + kg * 4;
        f32x4 bv = { bp[0], bp[1], bp[2], bp[3] };
#pragma unroll
        for (int j = 0; j < 12; ++j) acc[mf][j] = bv;
    }

    const _Float16* Xb = X + ((size_t)b * Pn + bx * 384) * 256;
    const _Float16* Wb = WT + (size_t)(co0 + wm * 32 + l15) * 256 + kg * 8;

    auto STAGE = [&](int c0, int bufo) {
        for (int i = wave; i < 24; i += 4) {
            int s = i / 6, wch = i - s * 6;
            int row_local = 8 + wch * 16 + (lane >> 2);
            int kchunk = (lane & 3) ^ ((row_local >> 1) & 3);
            const _Float16* src = Xb + ((size_t)(s * 96 + row_local - 8)) * 256 + c0 + kchunk * 8;
            char* dst = sm_raw + bufo + (s * 112 + 8 + wch * 16) * 64;
            GLOAD16(src, dst);
        }
    };
    auto LDA = [&](f16x8* slot, const _Float16* tp) {
#pragma unroll
        for (int mf = 0; mf < 2; ++mf) slot[mf] = *(const f16x8*)(tp + mf * 4096);
    };
    // one address per tap; stripe + fragment indices fold into ds_read offset immediates
    auto LDB = [&](f16x8* dst, const char* Bb, int T) {
        int rl0 = 3 + l15 + T; // swizzle term invariant in nf and stripe
        const char* bp = Bb + (wn * 224 + rl0) * 64 + ((kg ^ ((rl0 >> 1) & 3)) << 4);
#pragma unroll
        for (int s = 0; s < 2; ++s)
#pragma unroll
            for (int nf = 0; nf < 6; ++nf)
                dst[s * 6 + nf] = *(const f16x8*)(bp + s * 7168 + nf * 1024);
    };

    STAGE(0, 0);
    __syncthreads();

    int cur = 0;
    for (int s8 = 0; s8 < 8; ++s8) {
        const int c0 = s8 * 32;
        const _Float16* wc = Wb + c0;
        f16x8 afc[2], afn[2];
        LDA(afc, wc);
        if (s8 < 7) STAGE(c0 + 32, (cur ^ 1) * 28672);
        const char* Bb = sm_raw + cur * 28672;
        f16x8 bf[12];
#pragma unroll
        for (int t = 0; t < 11; ++t) {
            if (t < 10) LDA(afn, wc + (t + 1) * 65536);
            LDB(bf, Bb, t);
            __builtin_amdgcn_s_setprio(1);
#pragma unroll
            for (int mf = 0; mf < 2; ++mf)
#pragma unroll
                for (int j = 0; j < 12; ++j)
                    acc[mf][j] = __builtin_amdgcn_mfma_f32_16x16x32_f16(afc[mf], bf[j], acc[mf][j], 0, 0, 0);
            __builtin_amdgcn_s_setprio(0);
            if (t < 10) {
#pragma unroll
                for (int mf = 0; mf < 2; ++mf) afc[mf] = afn[mf];
            }
        }
        __syncthreads();
        cur ^= 1;
    }

    // epilogue: retile to channels-first fp16 via LDS [64][384]
    _Float16* sb = (_Float16*)sm_raw;
#pragma unroll
    for (int mf = 0; mf < 2; ++mf)
#pragma unroll
        for (int j = 0; j < 12; ++j)
#pragma unroll
            for (int r = 0; r < 4; ++r) {
                int row = wm * 32 + mf * 16 + kg * 4 + r;
                int p = wn * 192 + (j / 6) * 96 + (j % 6) * 16 + l15;
                sb[row * 384 + p] = (_Float16)acc[mf][j][r];
            }
    __syncthreads();
    for (int k = 0; k < 12; ++k) {
        int ci = tid + k * 256;           // 0..3071 chunks of 16B
        int row = ci / 48, ch = ci - row * 48;
        U4 v = *(const U4*)(sm_raw + row * 768 + ch * 16);
        *(U4*)(out + ((size_t)b * 256 + co0 + row) * Pn + bx * 384 + ch * 8) = v;
    }
}

// ---------- fused Q+K conv (both families in one dispatch): 2-pass fp16 ----------
__global__ __launch_bounds__(256, 2) void k_conv_qk(const _Float16* __restrict__ Xh0,
                                                    const _Float16* __restrict__ Xl0,
                                                    const _Float16* __restrict__ W0,
                                                    const float* __restrict__ bq0, const float* __restrict__ bk0,
                                                    _Float16* __restrict__ q0, _Float16* __restrict__ k0,
                                                    const _Float16* __restrict__ Xh1,
                                                    const _Float16* __restrict__ Xl1,
                                                    const _Float16* __restrict__ W1,
                                                    const float* __restrict__ bq1, const float* __restrict__ bk1,
                                                    _Float16* __restrict__ q1, _Float16* __restrict__ k1) {
    __shared__ char sm_raw[57344]; // 2 bufs x [4 stripes][112][64B]; epilogue aliases 24576B
    const int tid = threadIdx.x;
    const int lane = tid & 63, wave = tid >> 6;
    const int wm = wave >> 1, wn = wave & 1;
    const int l15 = lane & 15, kg = lane >> 4;
    // bijective XCD-chunked swizzle over grid (48,1,32): 1536 % 8 == 0
    int fid = blockIdx.x + 48 * blockIdx.z;
    int swz = (fid & 7) * 192 + (fid >> 3);
    const int bx = swz % 48;
    const int zz0 = swz / 48;
    const int fam = zz0 >> 4, b = zz0 & 15;
    const _Float16* Xh = fam ? Xh1 : Xh0;
    const _Float16* Xl = fam ? Xl1 : Xl0;
    const _Float16* WT = fam ? W1 : W0;
    const float* bq = fam ? bq1 : bq0;
    const float* bk = fam ? bk1 : bk0;
    _Float16* q16 = fam ? q1 : q0;
    _Float16* k16 = fam ? k1 : k0;

    for (int z = tid; z < 2048; z += 256) {
        int bufo = (z >> 10) * 28672;
        int s = (z >> 7) & 7, off = z & 127;
        int Rbase = (s >> 1) * 112 + ((s & 1) ? 104 : 0);
        *(unsigned*)(sm_raw + bufo + Rbase * 64 + off * 4) = 0u;
    }

    f32x4 acc[2][6];
#pragma unroll
    for (int mf = 0; mf < 2; ++mf) {
        int cb = wm * 32 + mf * 16 + kg * 4;
        f32x4 bv;
#pragma unroll
        for (int r = 0; r < 4; ++r) {
            int co_l = cb + r;
            bv[r] = (co_l < 32) ? bq[co_l] : bk[co_l - 32];
        }
#pragma unroll
        for (int nf = 0; nf < 6; ++nf) acc[mf][nf] = bv;
    }

    const _Float16* Xbh = Xh + ((size_t)b * Pn + bx * 192) * 256;
    const _Float16* Xbl = Xl + ((size_t)b * Pn + bx * 192) * 256;
    const _Float16* Wb = WT + (size_t)(wm * 32 + l15) * 256 + kg * 8;

    auto STAGE = [&](int c0, int bufo) {
        for (int i = wave; i < 24; i += 4) {
            int a = i / 12, rr = (i / 6) & 1, wch = i % 6;
            int row_local = 8 + wch * 16 + (lane >> 2);
            int kchunk = (lane & 3) ^ ((row_local >> 1) & 3);
            const _Float16* base = (a == 0) ? Xbh : Xbl;
            const _Float16* src = base + ((size_t)(rr * 96 + row_local - 8)) * 256 + c0 + kchunk * 8;
            char* dst = sm_raw + bufo + ((a * 2 + rr) * 112 + 8 + wch * 16) * 64;
            GLOAD16(src, dst);
        }
    };
    // one address per tap serves all 12 (hi+lo) fragment reads via offset immediates
    auto LDBHL = [&](f16x8* dh, f16x8* dl, const char* Bb, int T) {
        int rl0 = 3 + l15 + T;
        const char* bp = Bb + (wn * 112 + rl0) * 64 + ((kg ^ ((rl0 >> 1) & 3)) << 4);
#pragma unroll
        for (int nf = 0; nf < 6; ++nf) {
            dh[nf] = *(const f16x8*)(bp + nf * 1024);
            dl[nf] = *(const f16x8*)(bp + 14336 + nf * 1024);
        }
    };

    STAGE(0, 0);
    __syncthreads();

    int cur = 0;
    for (int s8 = 0; s8 < 8; ++s8) {
        const int c0 = s8 * 32;
        const _Float16* wc = Wb + c0;
        f16x8 afc[2], afn[2];
#pragma unroll
        for (int mf = 0; mf < 2; ++mf) afc[mf] = *(const f16x8*)(wc + mf * 4096);
        if (s8 < 7) STAGE(c0 + 32, (cur ^ 1) * 28672);
        const char* Bb = sm_raw + cur * 28672;
#pragma unroll
        for (int t = 0; t < 11; ++t) {
            if (t < 10) {
#pragma unroll
                for (int mf = 0; mf < 2; ++mf)
                    afn[mf] = *(const f16x8*)(wc + (t + 1) * 16384 + mf * 4096);
            }
            f16x8 bh[6], bl[6];
            LDBHL(bh, bl, Bb, t);
            __builtin_amdgcn_s_setprio(1);
#pragma unroll
            for (int mf = 0; mf < 2; ++mf)
#pragma unroll
                for (int nf = 0; nf < 6; ++nf) {
                    acc[mf][nf] = __builtin_amdgcn_mfma_f32_16x16x32_f16(afc[mf], bh[nf], acc[mf][nf], 0, 0, 0);
                    acc[mf][nf] = __builtin_amdgcn_mfma_f32_16x16x32_f16(afc[mf], bl[nf], acc[mf][nf], 0, 0, 0);
                }
            __builtin_amdgcn_s_setprio(0);
            if (t < 10) {
#pragma unroll
                for (int mf = 0; mf < 2; ++mf) afc[mf] = afn[mf];
            }
        }
        __syncthreads();
        cur ^= 1;
    }

    // epilogue: retile to [192 p][32 c] fp16 in LDS, then coalesced 16B stores
    __syncthreads();
    _Float16* sq = (_Float16*)sm_raw;            // [192][32]
    _Float16* sk = (_Float16*)(sm_raw + 12288);  // [192][32]
#pragma unroll
    for (int mf = 0; mf < 2; ++mf) {
        int cb = wm * 32 + mf * 16 + kg * 4;
#pragma unroll
        for (int r = 0; r < 4; ++r) {
            int co_l = cb + r;
            _Float16* arr = (co_l < 32) ? sq : sk;
            int c = co_l & 31;
#pragma unroll
            for (int nf = 0; nf < 6; ++nf) {
                int p = wn * 96 + nf * 16 + l15;
                arr[p * 32 + c] = (_Float16)acc[mf][nf][r];
            }
        }
    }
    __syncthreads();
    for (int j = 0; j < 6; ++j) {
        int idx = tid + j * 256;      // 0..1535 16B chunks
        int mtx = idx >= 768;
        int e = idx - mtx * 768;
        int p = e >> 2, cg2 = e & 3;
        U4 v = *(const U4*)(sm_raw + mtx * 12288 + p * 64 + cg2 * 16);
        _Float16* dstb = mtx ? k16 : q16;
        *(U4*)(dstb + ((size_t)b * Pn + bx * 192 + p) * 32 + cg2 * 8) = v;
    }
}

// ---------- attention helpers ----------
DI void stage_qk16(const _Float16* qg, const _Float16* kg, char* Lq, char* Lk, int tid) {
    for (int i = tid; i < 768; i += 256) {
        int mtx = i >= 384;
        int e = i - mtx * 384;
        int p = e >> 2, ch = e & 3;
        const _Float16* src = (mtx ? kg : qg) + p * 32 + ch * 8;
        f16x8 v = *(const f16x8*)src;
        char* dst = (mtx ? Lk : Lq) + p * 64 + ((ch ^ ((p >> 1) & 3)) << 4);
        *(f16x8*)dst = v;
    }
}

DI void mfma_e(const char* Lq, const char* Lk, float* Ef, int lane, int wave) {
    int l15 = lane & 15, kg = lane >> 4;
    int wm = wave >> 1, wn = wave & 1;
    f16x8 qa[3], kb[3];
#pragma unroll
    for (int i = 0; i < 3; ++i) {
        int pr = wm * 48 + i * 16 + l15;
        qa[i] = *(const f16x8*)(Lq + pr * 64 + ((kg ^ ((pr >> 1) & 3)) << 4));
        int pc = wn * 48 + i * 16 + l15;
        kb[i] = *(const f16x8*)(Lk + pc * 64 + ((kg ^ ((pc >> 1) & 3)) << 4));
    }
#pragma unroll
    for (int i = 0; i < 3; ++i)
#pragma unroll
        for (int j = 0; j < 3; ++j) {
            f32x4 a = { 0.f, 0.f, 0.f, 0.f };
            a = __builtin_amdgcn_mfma_f32_16x16x32_f16(qa[i], kb[j], a, 0, 0, 0);
#pragma unroll
            for (int r = 0; r < 4; ++r) {
                int row = wm * 48 + i * 16 + kg * 4 + r;
                int col = wn * 48 + j * 16 + l15;
                Ef[row * 97 + col] = a[r];
            }
        }
}

// ---------- P1: h-attention stats (per b,w), wave-parallel 2-way row split ----------
__global__ __launch_bounds__(256) void k_p1(const _Float16* __restrict__ q16, const _Float16* __restrict__ k16,
                                            float* __restrict__ mh, float* __restrict__ lh) {
    __shared__ char L[49536];
    float* Ef = (float*)L;
    char* Lq = L + 37248;
    char* Lk = L + 43392;
    const int tid = threadIdx.x, lane = tid & 63, wave = tid >> 6;
    const int w = blockIdx.x, b = blockIdx.y;
    const _Float16* qg = q16 + ((size_t)b * Pn + w * 96) * 32;
    const _Float16* kg = k16 + ((size_t)b * Pn + w * 96) * 32;
    stage_qk16(qg, kg, Lq, Lk, tid);
    __syncthreads();
    mfma_e(Lq, Lk, Ef, lane, wave);
    __syncthreads();
    if (tid < 96) Ef[tid * 97 + tid] = -INFINITY; // diag mask
    __syncthreads();
    float* red  = (float*)Lq;  // dead after mfma_e
    float* red2 = red + 192;
    if (tid < 192) {
        int r = tid >> 1, hf = tid & 1;
        const float* er = Ef + r * 97 + hf * 48;
        float m = -INFINITY;
        for (int j = 0; j < 48; ++j) m = fmaxf(m, er[j]);
        red[tid] = m;
    }
    __syncthreads();
    if (tid < 192) {
        int r = tid >> 1, hf = tid & 1;
        float m = fmaxf(red[r * 2], red[r * 2 + 1]);
        const float* er = Ef + r * 97 + hf * 48;
        float s = 0.f;
        for (int j = 0; j < 48; ++j) s += __expf(er[j] - m);
        red2[tid] = s;
    }
    __syncthreads();
    if (tid < 96) {
        mh[((size_t)b * 96 + w) * 96 + tid] = fmaxf(red[tid * 2], red[tid * 2 + 1]);
        lh[((size_t)b * 96 + w) * 96 + tid] = red2[tid * 2] + red2[tid * 2 + 1];
    }
}

// ---------- P2: w-attention stats+merge+PV (per b,h); writes out_w fp16 to scratch ----------
__global__ __launch_bounds__(256) void k_p2(const _Float16* __restrict__ q16, const _Float16* __restrict__ k16,
                                            const _Float16* __restrict__ V,
                                            const float* __restrict__ mh, const float* __restrict__ lh,
                                            float* __restrict__ mo, float* __restrict__ lo,
                                            _Float16* __restrict__ outw) {
    __shared__ char L[56448];
    float* Ef = (float*)L;          // [96][97] f32
    char* LA  = L + 37248;          // A fp16 [96][12 chunks]
    char* Lq  = L + 37248;          // overlaps LA (dead before A written)
    char* Lk  = L + 43392;
    float* Marr = (float*)(L + 55680);
    float* Linv = (float*)(L + 56064);
    const int tid = threadIdx.x, lane = tid & 63, wave = tid >> 6;
    const int l15 = lane & 15, kg = lane >> 4;
    const int h = blockIdx.x, b = blockIdx.y;
    const _Float16* qg = q16 + ((size_t)b * Pn + h * 96) * 32;
    const _Float16* kgp = k16 + ((size_t)b * Pn + h * 96) * 32;
    stage_qk16(qg, kgp, Lq, Lk, tid);
    __syncthreads();
    mfma_e(Lq, Lk, Ef, lane, wave);
    __syncthreads();
    float* red  = (float*)Lk;  // dead after mfma_e; A-build happens later
    float* red2 = red + 192;
    if (tid < 192) {
        int r = tid >> 1, hf = tid & 1;
        const float* er = Ef + r * 97 + hf * 48;
        float m = -INFINITY;
        for (int j = 0; j < 48; ++j) m = fmaxf(m, er[j]);
        red[tid] = m;
    }
    __syncthreads();
    if (tid < 192) {
        int r = tid >> 1, hf = tid & 1;
        float m = fmaxf(red[r * 2], red[r * 2 + 1]);
        const float* er = Ef + r * 97 + hf * 48;
        float s = 0.f;
        for (int j = 0; j < 48; ++j) s += __expf(er[j] - m);
        red2[tid] = s;
    }
    __syncthreads();
    if (tid < 96) {
        int wq = tid;
        float mw = fmaxf(red[wq * 2], red[wq * 2 + 1]);
        float lw = red2[wq * 2] + red2[wq * 2 + 1];
        float mhv = mh[((size_t)b * 96 + wq) * 96 + h];
        float lhv = lh[((size_t)b * 96 + wq) * 96 + h];
        float m = fmaxf(mhv, mw);
        float l = lhv * __expf(mhv - m) + lw * __expf(mw - m);
        mo[((size_t)b * 96 + h) * 96 + wq] = m;
        lo[((size_t)b * 96 + h) * 96 + wq] = l;
        Marr[wq] = m;
        Linv[wq] = 1.f / l;
    }
    __syncthreads();
    if (tid < 192) {
        int r = tid >> 1, half = tid & 1;
        float m = Marr[r], li = Linv[r];
        const float* er = Ef + r * 97;
        for (int cc = 0; cc < 6; ++cc) {
            int chunk = half * 6 + cc;
            f16x8 av;
#pragma unroll
            for (int jj = 0; jj < 8; ++jj)
                av[jj] = (_Float16)(__expf(er[chunk * 8 + jj] - m) * li);
            *(f16x8*)(LA + r * 192 + ((chunk ^ ((r >> 1) & 3)) << 4)) = av;
        }
    }
    __syncthreads();
    // PV: out_w[c][wq] = sum_W V[c][W] * A[wq][W]
    f32x4 acc[4][6];
#pragma unroll
    for (int mf = 0; mf < 4; ++mf)
#pragma unroll
        for (int nf = 0; nf < 6; ++nf) acc[mf][nf] = f32x4{ 0.f, 0.f, 0.f, 0.f };
    const _Float16* vb = V + ((size_t)b * 256 + wave * 64 + l15) * Pn + h * 96 + kg * 8;
    f16x8 va[4][3];
#pragma unroll
    for (int mf = 0; mf < 4; ++mf)
#pragma unroll
        for (int ks = 0; ks < 3; ++ks)
            va[mf][ks] = *(const f16x8*)(vb + (size_t)mf * 16 * Pn + ks * 32);
#pragma unroll
    for (int ks = 0; ks < 3; ++ks)
#pragma unroll
        for (int nf = 0; nf < 6; ++nf) {
            int wq = nf * 16 + l15;
            int chunk = ks * 4 + kg;
            f16x8 bv = *(const f16x8*)(LA + wq * 192 + ((chunk ^ ((wq >> 1) & 3)) << 4));
#pragma unroll
            for (int mf = 0; mf < 4; ++mf)
                acc[mf][nf] = __builtin_amdgcn_mfma_f32_16x16x32_f16(va[mf][ks], bv, acc[mf][nf], 0, 0, 0);
        }
    _Float16* ob = outw + ((size_t)b * 256) * Pn + h * 96;
#pragma unroll
    for (int mf = 0; mf < 4; ++mf)
#pragma unroll
        for (int nf = 0; nf < 6; ++nf)
#pragma unroll
            for (int r = 0; r < 4; ++r) {
                int c = wave * 64 + mf * 16 + kg * 4 + r;
                ob[(size_t)c * Pn + nf * 16 + l15] = (_Float16)acc[mf][nf][r];
            }
}

// ---------- P3: h-attention PV (per b,w); writes pT fp16 [b][c][w*96+h] ----------
__global__ __launch_bounds__(256) void k_p3(const _Float16* __restrict__ q16, const _Float16* __restrict__ k16,
                                            const _Float16* __restrict__ V,
                                            const float* __restrict__ mo, const float* __restrict__ lo,
                                            _Float16* __restrict__ pT) {
    __shared__ char L[56448];
    float* Ef = (float*)L;
    char* LA  = L + 37248;
    char* Lq  = L + 37248;
    char* Lk  = L + 43392;
    float* Marr = (float*)(L + 55680);
    float* Linv = (float*)(L + 56064);
    const int tid = threadIdx.x, lane = tid & 63, wave = tid >> 6;
    const int l15 = lane & 15, kg = lane >> 4;
    const int w = blockIdx.x, b = blockIdx.y;
    const _Float16* qg = q16 + ((size_t)b * Pn + w * 96) * 32;
    const _Float16* kgp = k16 + ((size_t)b * Pn + w * 96) * 32;
    stage_qk16(qg, kgp, Lq, Lk, tid);
    __syncthreads();
    mfma_e(Lq, Lk, Ef, lane, wave);
    __syncthreads();
    if (tid < 96) {
        int hq = tid;
        Marr[hq] = mo[((size_t)b * 96 + hq) * 96 + w];
        Linv[hq] = 1.f / lo[((size_t)b * 96 + hq) * 96 + w];
    }
    __syncthreads();
    if (tid < 192) {
        int r = tid >> 1, half = tid & 1;
        float m = Marr[r], li = Linv[r];
        const float* er = Ef + r * 97;
        for (int cc = 0; cc < 6; ++cc) {
            int chunk = half * 6 + cc;
            f16x8 av;
#pragma unroll
            for (int jj = 0; jj < 8; ++jj) {
                int col = chunk * 8 + jj;
                av[jj] = (col == r) ? (_Float16)0.f
                                    : (_Float16)(__expf(er[col] - m) * li);
            }
            *(f16x8*)(LA + r * 192 + ((chunk ^ ((r >> 1) & 3)) << 4)) = av;
        }
    }
    __syncthreads();
    f32x4 acc[4][6];
#pragma unroll
    for (int mf = 0; mf < 4; ++mf)
#pragma unroll
        for (int nf = 0; nf < 6; ++nf) acc[mf][nf] = f32x4{ 0.f, 0.f, 0.f, 0.f };
    const _Float16* vb = V + ((size_t)b * 256 + wave * 64 + l15) * Pn + w * 96 + kg * 8;
    f16x8 va[4][3];
#pragma unroll
    for (int mf = 0; mf < 4; ++mf)
#pragma unroll
        for (int ks = 0; ks < 3; ++ks)
            va[mf][ks] = *(const f16x8*)(vb + (size_t)mf * 16 * Pn + ks * 32);
#pragma unroll
    for (int ks = 0; ks < 3; ++ks)
#pragma unroll
        for (int nf = 0; nf < 6; ++nf) {
            int hq = nf * 16 + l15;
            int chunk = ks * 4 + kg;
            f16x8 bv = *(const f16x8*)(LA + hq * 192 + ((chunk ^ ((hq >> 1) & 3)) << 4));
#pragma unroll
            for (int mf = 0; mf < 4; ++mf)
                acc[mf][nf] = __builtin_amdgcn_mfma_f32_16x16x32_f16(va[mf][ks], bv, acc[mf][nf], 0, 0, 0);
        }
    _Float16* pb = pT + ((size_t)b * 256) * Pn + w * 96;
#pragma unroll
    for (int mf = 0; mf < 4; ++mf)
#pragma unroll
        for (int nf = 0; nf < 6; ++nf)
#pragma unroll
            for (int r = 0; r < 4; ++r) {
                int c = wave * 64 + mf * 16 + kg * 4 + r;
                pb[(size_t)c * Pn + nf * 16 + l15] = (_Float16)acc[mf][nf][r];
            }
}

// ---------- combine: out = gamma * (pT^T + out_w) + x ----------
__global__ __launch_bounds__(256) void k_combine(const _Float16* __restrict__ pT,
                                                 const _Float16* __restrict__ ow,
                                                 const float* __restrict__ x,
                                                 const float* __restrict__ gamma,
                                                 float* __restrict__ out) {
    __shared__ float T[32][33];
    int bh = blockIdx.x, bw = blockIdx.y;
    size_t ib = (size_t)blockIdx.z * Pn;
    int tx = threadIdx.x, ty = threadIdx.y;
#pragma unroll
    for (int i = 0; i < 4; ++i) {
        int r = bw * 32 + ty + i * 8;
        T[ty + i * 8][tx] = (float)pT[ib + (size_t)r * 96 + bh * 32 + tx];
    }
    __syncthreads();
    float g = gamma[0];
#pragma unroll
    for (int i = 0; i < 4; ++i) {
        int hh = bh * 32 + ty + i * 8, ww = bw * 32 + tx;
        size_t o = ib + (size_t)hh * 96 + ww;
        out[o] = g * (T[tx][ty + i * 8] + (float)ow[o]) + x[o];
    }
}

extern "C" void kernel_launch(void* const* d_in, const int* in_sizes, int n_in,
                              void* d_out, int out_size, void* d_ws, size_t ws_size,
                              hipStream_t stream) {
    (void)in_sizes; (void)n_in; (void)out_size; (void)ws_size;
    const float* x   = (const float*)d_in[0];
    const float* wqh = (const float*)d_in[1];
    const float* bqh = (const float*)d_in[2];
    const float* wqw = (const float*)d_in[3];
    const float* bqw = (const float*)d_in[4];
    const float* wkh = (const float*)d_in[5];
    const float* bkh = (const float*)d_in[6];
    const float* wkw = (const float*)d_in[7];
    const float* bkw = (const float*)d_in[8];
    const float* wvh = (const float*)d_in[9];
    const float* bvh = (const float*)d_in[10];
    const float* wvw = (const float*)d_in[11];
    const float* bvw = (const float*)d_in[12];
    const float* gam = (const float*)d_in[13];
    float* out = (float*)d_out;

    char* ws = (char*)d_ws;
    size_t off = 0;
    auto alloc = [&](size_t bytes) -> char* {
        char* p = ws + off;
        off = (off + bytes + 255) & ~(size_t)255;
        return p;
    };
    const size_t IMG = (size_t)Bn * Cn * Pn;
    const size_t QK16 = (size_t)Bn * Pn * 32; // fp16 elements

    _Float16* xh  = (_Float16*)alloc(IMG * 2);
    _Float16* xl  = (_Float16*)alloc(IMG * 2);
    _Float16* xhT = (_Float16*)alloc(IMG * 2);
    _Float16* xlT = (_Float16*)alloc(IMG * 2);
    _Float16* qh16 = (_Float16*)alloc(QK16 * 2);
    _Float16* kh16 = (_Float16*)alloc(QK16 * 2);
    _Float16* qw16 = (_Float16*)alloc(QK16 * 2);
    _Float16* kw16 = (_Float16*)alloc(QK16 * 2);
    float* mh = (float*)alloc((size_t)Bn * Pn * 4);
    float* lh = (float*)alloc((size_t)Bn * Pn * 4);
    float* mo = (float*)alloc((size_t)Bn * Pn * 4);
    float* lo = (float*)alloc((size_t)Bn * Pn * 4);
    _Float16* wqkh  = (_Float16*)alloc((size_t)11 * 64 * 256 * 2);
    _Float16* wqkw  = (_Float16*)alloc((size_t)11 * 64 * 256 * 2);
    _Float16* wvh16 = (_Float16*)alloc((size_t)11 * 256 * 256 * 2);
    _Float16* wvw16 = (_Float16*)alloc((size_t)11 * 256 * 256 * 2);
    // aliases (stream-ordered safe): V outputs overwrite lo-split inputs after qk convs;
    // pT overwrites xhT after all h-family convs; out_w fp16 overwrites xh after all convs.
    _Float16* vh = xlT;
    _Float16* vw = xl;
    _Float16* pT = xhT;
    _Float16* ow16 = xh;

    const int gq = (32 * 2816 + 255) / 256;
    const int gv = (256 * 2816 + 255) / 256;
    k_wt16<<<gq, 256, 0, stream>>>(wqh, wqkh, 32, 0, 64);
    k_wt16<<<gq, 256, 0, stream>>>(wkh, wqkh, 32, 32, 64);
    k_wt16<<<gq, 256, 0, stream>>>(wqw, wqkw, 32, 0, 64);
    k_wt16<<<gq, 256, 0, stream>>>(wkw, wqkw, 32, 32, 64);
    k_wt16<<<gv, 256, 0, stream>>>(wvh, wvh16, 256, 0, 256);
    k_wt16<<<gv, 256, 0, stream>>>(wvw, wvw16, 256, 0, 256);

    k_xsplit<<<dim3(72, 16), 256, 0, stream>>>(x, xh, xl, xhT, xlT);

    k_conv_qk<<<dim3(48, 1, 32), 256, 0, stream>>>(xhT, xlT, wqkh, bqh, bkh, qh16, kh16,
                                                   xh,  xl,  wqkw, bqw, bkw, qw16, kw16);
    k_conv_v <<<dim3(24, 4, 32), 256, 0, stream>>>(xhT, wvh16, bvh, vh,
                                                   xh,  wvw16, bvw, vw);

    k_p1<<<dim3(96, 16), 256, 0, stream>>>(qh16, kh16, mh, lh);
    k_p2<<<dim3(96, 16), 256, 0, stream>>>(qw16, kw16, vw, mh, lh, mo, lo, ow16);
    k_p3<<<dim3(96, 16), 256, 0, stream>>>(qh16, kh16, vh, mo, lo, pT);

    k_combine<<<dim3(3, 3, Bn * Cn), dim3(32, 8), 0, stream>>>(pT, ow16, x, gam, out);
}